// Round 8
// baseline (136.293 us; speedup 1.0000x reference)
//
#include <hip/hip_runtime.h>
#include <math.h>

// Problem constants: [N, L, H, D] = [4, 8192, 8, 64], Dv = 64, fp32 in/out.
#define N_    4
#define L_    8192
#define H_    8
#define NH_   32           // N*H
#define CHK   64           // chunk length
#define NC_   128          // chunks per (n,h)
#define ROWF  512          // H_*D_ floats between consecutive l
#define EPSF  1e-6f

typedef __attribute__((ext_vector_type(8))) short bf16x8;   // 8 bf16 = 4 VGPRs
typedef __attribute__((ext_vector_type(4))) float f32x4;
typedef __attribute__((ext_vector_type(4))) unsigned short us4;

__device__ __forceinline__ float fmap(float x) { return x > 0.f ? x + 1.f : __expf(x); }

__device__ __forceinline__ unsigned short f2bf(float x) {
  unsigned u = __float_as_uint(x);
  u += 0x7FFFu + ((u >> 16) & 1u);       // round-to-nearest-even
  return (unsigned short)(u >> 16);
}
__device__ __forceinline__ float bf2f(unsigned short u) {
  return __uint_as_float(((unsigned)u) << 16);
}

// Swizzled ushort index into a row-major [64] bf16 tile (row stride 128 B).
// All ws tiles are stored in this same swizzled image, so copies are linear.
__device__ __forceinline__ int sidx(int row, int col) {
  return row * 64 + (col ^ ((row & 7) << 3));
}

__device__ __forceinline__ f32x4 MFMA(bf16x8 a, bf16x8 b, f32x4 c) {
  return __builtin_amdgcn_mfma_f32_16x16x32_bf16(a, b, c, 0, 0, 0);
}

// ---------------- Pass A: per-chunk totals + bf16 K̂/V̂t handoff ----------------
__global__ __launch_bounds__(256) void k_chunk_tot(const float* __restrict__ keys,
                                                   const float* __restrict__ values,
                                                   unsigned short* __restrict__ Tws,
                                                   unsigned short* __restrict__ Khat,
                                                   unsigned short* __restrict__ Vhat,
                                                   float* __restrict__ Kcs) {
  __shared__ __align__(16) unsigned short Kt[64 * 64];  // K^T [d][s] (fmap, bf16)
  __shared__ __align__(16) unsigned short Vt[64 * 64];  // V^T [e][s]
  __shared__ float kacc[64];
  const int bid = blockIdx.x;             // nh*NC_ + c
  const int nh = bid / NC_, c = bid % NC_;
  const int n = nh / H_, h = nh % H_;
  const int tid = threadIdx.x;
  const int lane = tid & 63;
  const int wv = tid >> 6;
  const int lane15 = lane & 15, lg = lane >> 4;
  const int arow = wv * 16 + lane15;      // e-row for the V fragment

  if (tid < 64) kacc[tid] = 0.f;

  // transposed staging (coalesced: lanes 0..63 read consecutive floats per s);
  // V̂t handed off straight from registers (swizzled image).
  float kpart = 0.f;
  {
    const int d = tid & 63, sg = tid >> 6;
    const size_t gbase = ((size_t)(n * L_ + c * CHK)) * ROWF + h * 64 + d;
    unsigned short* Vp = Vhat + (size_t)bid * 4096;
    for (int rep = 0; rep < 4; ++rep) {
      const int s0 = (sg * 4 + rep) * 4;
      us4 wk, wvv;
#pragma unroll
      for (int j = 0; j < 4; ++j) {
        const size_t g = gbase + (size_t)(s0 + j) * ROWF;
        const float kf = fmap(keys[g]);
        kpart += kf;
        wk[j] = f2bf(kf);
        wvv[j] = f2bf(values[g]);
      }
      *(us4*)&Kt[sidx(d, s0)] = wk;
      *(us4*)&Vt[sidx(d, s0)] = wvv;
      *(us4*)&Vp[sidx(d, s0)] = wvv;     // handoff (fire-and-forget)
    }
  }
  __syncthreads();  // B1: tiles + kacc zero-init visible

  atomicAdd(&kacc[tid & 63], kpart);

  // swapped MFMA: lane holds T[e = arow][d = nt*16 + lg*4 + r]; store swizzled
  const bf16x8 av0 = *(const bf16x8*)&Vt[sidx(arow, lg * 8)];
  const bf16x8 av1 = *(const bf16x8*)&Vt[sidx(arow, (lg + 4) * 8)];
  unsigned short* Tp = Tws + (size_t)bid * 4096;
#pragma unroll
  for (int nt = 0; nt < 4; ++nt) {
    const int brow = nt * 16 + lane15;   // d-window
    f32x4 acc = {0.f, 0.f, 0.f, 0.f};
    acc = MFMA(*(const bf16x8*)&Kt[sidx(brow, lg * 8)], av0, acc);
    acc = MFMA(*(const bf16x8*)&Kt[sidx(brow, (lg + 4) * 8)], av1, acc);
    us4 w;
#pragma unroll
    for (int r = 0; r < 4; ++r) w[r] = f2bf(acc[r]);
    *(us4*)&Tp[sidx(arow, nt * 16 + lg * 4)] = w;
  }

  // K̂ handoff: transpose Kt -> row-major [s][d], swizzled image.
  {
    unsigned short* Kp = Khat + (size_t)bid * 4096;
    const int s = tid >> 2, dd4 = (tid & 3) * 16;
    unsigned short val[16];
#pragma unroll
    for (int m = 0; m < 16; ++m) val[m] = Kt[sidx(dd4 + m, s)];
#pragma unroll
    for (int q = 0; q < 4; ++q) {
      us4 w;
#pragma unroll
      for (int r = 0; r < 4; ++r) w[r] = val[q * 4 + r];
      *(us4*)&Kp[sidx(s, dd4 + q * 4)] = w;
    }
  }
  __syncthreads();  // atomics done
  if (tid < 64) Kcs[(size_t)bid * 64 + tid] = kacc[tid];
}

// ---------------- Pass B: in-place exclusive prefix over chunks (depth 32, 4-wide) ----------------
// Operates per fixed linear element index; swizzle is a fixed within-tile
// permutation, so the elementwise scan is unaffected.
__global__ __launch_bounds__(256) void k_scan(unsigned short* __restrict__ Tws,
                                              float* __restrict__ Kcs) {
  const int tid = threadIdx.x;
  if (blockIdx.x < 512) {
    const int gid = blockIdx.x * 256 + tid;          // 0 .. 131071
    const int nh = gid >> 12, de = gid & 4095;
    unsigned short* p = Tws + (size_t)nh * NC_ * 4096 + de;
    float run = 0.f;
    for (int s = 0; s < 32; ++s) {
      const float x0 = bf2f(p[(size_t)(s * 4 + 0) * 4096]);
      const float x1 = bf2f(p[(size_t)(s * 4 + 1) * 4096]);
      const float x2 = bf2f(p[(size_t)(s * 4 + 2) * 4096]);
      const float x3 = bf2f(p[(size_t)(s * 4 + 3) * 4096]);
      p[(size_t)(s * 4 + 0) * 4096] = f2bf(run);
      p[(size_t)(s * 4 + 1) * 4096] = f2bf(run + x0);
      p[(size_t)(s * 4 + 2) * 4096] = f2bf(run + x0 + x1);
      p[(size_t)(s * 4 + 3) * 4096] = f2bf(run + x0 + x1 + x2);
      run += x0 + x1 + x2 + x3;
    }
  } else {
    const int gid = (blockIdx.x - 512) * 256 + tid;  // 0 .. 2047
    const int nh = gid >> 6, d = gid & 63;
    float* p = Kcs + (size_t)nh * NC_ * 64 + d;
    float run = 0.f;
    for (int s = 0; s < 32; ++s) {
      const float x0 = p[(size_t)(s * 4 + 0) * 64];
      const float x1 = p[(size_t)(s * 4 + 1) * 64];
      const float x2 = p[(size_t)(s * 4 + 2) * 64];
      const float x3 = p[(size_t)(s * 4 + 3) * 64];
      p[(size_t)(s * 4 + 0) * 64] = run;
      p[(size_t)(s * 4 + 1) * 64] = run + x0;
      p[(size_t)(s * 4 + 2) * 64] = run + x0 + x1;
      p[(size_t)(s * 4 + 3) * 64] = run + x0 + x1 + x2;
      run += x0 + x1 + x2 + x3;
    }
  }
}

// ---------------- Pass C: per-chunk output; staging = linear uint4 copies ----------------
__global__ __launch_bounds__(256, 6) void k_output(const float* __restrict__ queries,
                                                   const unsigned short* __restrict__ Khat,
                                                   const unsigned short* __restrict__ Vhat,
                                                   const unsigned short* __restrict__ Pws,
                                                   const float* __restrict__ Kpre,
                                                   float* __restrict__ out) {
  __shared__ __align__(16) unsigned short Ks[64 * 64];  // K̂ (fmap'd); after B2: attn rows
  __shared__ __align__(16) unsigned short Vt[64 * 64];  // V̂^T [e][s]
  __shared__ __align__(16) unsigned short St[64 * 64];  // S^T prefix [e][d]
  __shared__ float kpre[64];

  // XCD-aware swizzle: 4096 % 8 == 0 -> bijective
  const int wg = blockIdx.x;
  const int bid = (wg & 7) * (NH_ * NC_ / 8) + (wg >> 3);
  const int nh = bid / NC_, c = bid % NC_;
  const int n = nh / H_, h = nh % H_;
  const int tid = threadIdx.x;
  const int lane = tid & 63;
  const int wv = tid >> 6;
  const int lane15 = lane & 15, lg = lane >> 4;
  const int t0w = wv * 16;
  const int trow = t0w + lane15;          // this lane's attn/output row (wave-local)
  const int l0 = c * CHK;

  // Q fragments straight into registers (issued first: longest dep chain)
  bf16x8 qf0, qf1;
  {
    const size_t qg = ((size_t)(n * L_ + l0 + trow)) * ROWF + h * 64;
    const float4 a = *(const float4*)&queries[qg + lg * 8];
    const float4 b = *(const float4*)&queries[qg + lg * 8 + 4];
    const float4 cc = *(const float4*)&queries[qg + 32 + lg * 8];
    const float4 d4 = *(const float4*)&queries[qg + 32 + lg * 8 + 4];
    qf0[0] = (short)f2bf(fmap(a.x)); qf0[1] = (short)f2bf(fmap(a.y));
    qf0[2] = (short)f2bf(fmap(a.z)); qf0[3] = (short)f2bf(fmap(a.w));
    qf0[4] = (short)f2bf(fmap(b.x)); qf0[5] = (short)f2bf(fmap(b.y));
    qf0[6] = (short)f2bf(fmap(b.z)); qf0[7] = (short)f2bf(fmap(b.w));
    qf1[0] = (short)f2bf(fmap(cc.x)); qf1[1] = (short)f2bf(fmap(cc.y));
    qf1[2] = (short)f2bf(fmap(cc.z)); qf1[3] = (short)f2bf(fmap(cc.w));
    qf1[4] = (short)f2bf(fmap(d4.x)); qf1[5] = (short)f2bf(fmap(d4.y));
    qf1[6] = (short)f2bf(fmap(d4.z)); qf1[7] = (short)f2bf(fmap(d4.w));
  }
  // Linear 16B copies of the pre-swizzled tiles (images identical in LDS)
  {
    const size_t tb = (size_t)bid * 4096;
#pragma unroll
    for (int it = 0; it < 2; ++it) {
      const int i8 = (tid + it * 256) * 8;
      *(uint4*)&Ks[i8] = *(const uint4*)&Khat[tb + i8];
      *(uint4*)&Vt[i8] = *(const uint4*)&Vhat[tb + i8];
      *(uint4*)&St[i8] = *(const uint4*)&Pws[tb + i8];
    }
  }
  if (tid < 64) kpre[tid] = Kpre[(size_t)bid * 64 + tid];
  __syncthreads();  // B1: all tiles + kpre visible

  // ---- QK^T, swapped: lane holds attn[t = trow][s = nt*16 + lg*4 + r] ----
  f32x4 aT[4];
#pragma unroll
  for (int nt = 0; nt < 4; ++nt) {
    const int srow = nt * 16 + lane15;
    f32x4 a = {0.f, 0.f, 0.f, 0.f};
    a = MFMA(*(const bf16x8*)&Ks[sidx(srow, lg * 8)], qf0, a);
    a = MFMA(*(const bf16x8*)&Ks[sidx(srow, (lg + 4) * 8)], qf1, a);
    aT[nt] = a;
  }
  // zden inter-chunk term: in-register dot Q[trow] . kpre
  float zp = 0.f;
#pragma unroll
  for (int j = 0; j < 8; ++j) zp += bf2f((unsigned short)qf0[j]) * kpre[lg * 8 + j];
#pragma unroll
  for (int j = 0; j < 8; ++j) zp += bf2f((unsigned short)qf1[j]) * kpre[32 + lg * 8 + j];

  __syncthreads();  // B2: all waves' Ks reads done (Ks becomes the attn buffer)

  // ---- mask + rowsum + attn rows into Ks (wave-local rows) ----
  float rs = 0.f;
#pragma unroll
  for (int nt = 0; nt < 4; ++nt) {
    us4 w;
#pragma unroll
    for (int r = 0; r < 4; ++r) {
      const int s = nt * 16 + lg * 4 + r;
      const float v = (s <= trow) ? aT[nt][r] : 0.f;
      rs += v;
      w[r] = f2bf(v);
    }
    *(us4*)&Ks[sidx(trow, nt * 16 + lg * 4)] = w;
  }
  // denominator for row trow: reduce the 4 lg-partials; zv stays lane-local
  float den = rs + zp;
  den += __shfl_xor(den, 16);
  den += __shfl_xor(den, 32);
  const float zv = 1.f / (den + EPSF);

  // ---- out^T-frags: lane holds out[trow][e = nt*16 + lg*4 + r] -> float4 stores ----
  const bf16x8 af0 = *(const bf16x8*)&Ks[sidx(trow, lg * 8)];
  const bf16x8 af1 = *(const bf16x8*)&Ks[sidx(trow, 32 + lg * 8)];
  const size_t obase = ((size_t)(n * L_ + l0 + trow)) * ROWF + h * 64;
#pragma unroll
  for (int nt = 0; nt < 4; ++nt) {
    const int brow = nt * 16 + lane15;   // Vt/St row (e) window
    f32x4 o = {0.f, 0.f, 0.f, 0.f};
    o = MFMA(*(const bf16x8*)&Vt[sidx(brow, lg * 8)], af0, o);
    o = MFMA(*(const bf16x8*)&Vt[sidx(brow, (lg + 4) * 8)], af1, o);
    o = MFMA(*(const bf16x8*)&St[sidx(brow, lg * 8)], qf0, o);
    o = MFMA(*(const bf16x8*)&St[sidx(brow, (lg + 4) * 8)], qf1, o);
    const float4 w = make_float4(o[0] * zv, o[1] * zv, o[2] * zv, o[3] * zv);
    *(float4*)&out[obase + nt * 16 + lg * 4] = w;
  }
}

extern "C" void kernel_launch(void* const* d_in, const int* in_sizes, int n_in,
                              void* d_out, int out_size, void* d_ws, size_t ws_size,
                              hipStream_t stream) {
  const float* queries = (const float*)d_in[0];
  const float* keys    = (const float*)d_in[1];
  const float* values  = (const float*)d_in[2];
  float* out = (float*)d_out;

  // workspace layout (all chunk tiles stored in the swizzled sidx image):
  //  Tws  [NH_*NC_][4096] bf16  (chunk totals -> in-place exclusive prefixes)
  //  Khat [NH_*NC_][4096] bf16  (fmap'd K, row-major [s][d])
  //  Vhat [NH_*NC_][4096] bf16  (V^T [e][s])
  //  Kcs  [NH_*NC_][64]   fp32  (chunk colsums -> exclusive prefixes)
  const size_t t_elems = (size_t)NH_ * NC_ * 4096;   // 16.7M bf16 = 33.5 MB each
  const size_t k_elems = (size_t)NH_ * NC_ * 64;
  if (ws_size < t_elems * 2 * 3 + k_elems * 4) return;
  unsigned short* Tws  = (unsigned short*)d_ws;
  unsigned short* Khat = Tws + t_elems;
  unsigned short* Vhat = Khat + t_elems;
  float* Kcs = (float*)(Vhat + t_elems);

  hipLaunchKernelGGL(k_chunk_tot, dim3(NH_ * NC_), dim3(256), 0, stream,
                     keys, values, Tws, Khat, Vhat, Kcs);
  hipLaunchKernelGGL(k_scan, dim3(512 + 8), dim3(256), 0, stream, Tws, Kcs);
  hipLaunchKernelGGL(k_output, dim3(NH_ * NC_), dim3(256), 0, stream,
                     queries, Khat, Vhat, Tws, Kcs, out);
}

// Round 9
// 92.465 us; speedup vs baseline: 1.4740x; 1.4740x over previous
//
#include <hip/hip_runtime.h>
#include <math.h>

// Problem constants: [N, L, H, D] = [4, 8192, 8, 64], Dv = 64, fp32 in/out.
#define N_    4
#define L_    8192
#define H_    8
#define NH_   32           // N*H
#define CHK   64           // chunk length
#define NC_   128          // chunks per (n,h)
#define ROWF  512          // H_*D_ floats between consecutive l
#define EPSF  1e-6f

typedef __attribute__((ext_vector_type(8))) short bf16x8;   // 8 bf16 = 4 VGPRs
typedef __attribute__((ext_vector_type(4))) float f32x4;
typedef __attribute__((ext_vector_type(4))) unsigned short us4;

__device__ __forceinline__ float fmap(float x) { return x > 0.f ? x + 1.f : __expf(x); }

__device__ __forceinline__ unsigned short f2bf(float x) {
  unsigned u = __float_as_uint(x);
  u += 0x7FFFu + ((u >> 16) & 1u);       // round-to-nearest-even
  return (unsigned short)(u >> 16);
}
__device__ __forceinline__ float bf2f(unsigned short u) {
  return __uint_as_float(((unsigned)u) << 16);
}

// Swizzled ushort index into a row-major [64] bf16 tile (row stride 128 B).
// ws tiles (Tws) are stored in this same swizzled image -> linear copies.
__device__ __forceinline__ int sidx(int row, int col) {
  return row * 64 + (col ^ ((row & 7) << 3));
}

__device__ __forceinline__ f32x4 MFMA(bf16x8 a, bf16x8 b, f32x4 c) {
  return __builtin_amdgcn_mfma_f32_16x16x32_bf16(a, b, c, 0, 0, 0);
}

// ---------------- Pass A: per-chunk totals T_c = (K^T V)^T and K column-sums ----------------
// Prefetch-all staging (single vmcnt drain) + coalesced T-store via LDS.
__global__ __launch_bounds__(256, 4) void k_chunk_tot(const float* __restrict__ keys,
                                                      const float* __restrict__ values,
                                                      unsigned short* __restrict__ Tws,
                                                      float* __restrict__ Kcs) {
  __shared__ __align__(16) unsigned short Kt[64 * 64];  // K^T [d][s] (fmap, bf16); later: T tile
  __shared__ __align__(16) unsigned short Vt[64 * 64];  // V^T [e][s]
  __shared__ float kacc[64];
  const int bid = blockIdx.x;             // nh*NC_ + c
  const int nh = bid / NC_, c = bid % NC_;
  const int n = nh / H_, h = nh % H_;
  const int tid = threadIdx.x;
  const int lane = tid & 63;
  const int wv = tid >> 6;
  const int lane15 = lane & 15, lg = lane >> 4;
  const int arow = wv * 16 + lane15;      // e-row for the V fragment

  if (tid < 64) kacc[tid] = 0.f;

  // ---- prefetch: all 32 floats into registers (coalesced across lanes) ----
  const int d = tid & 63, sg = tid >> 6;
  const size_t gbase = ((size_t)(n * L_ + c * CHK)) * ROWF + h * 64 + d;
  float kr[16], vr[16];
#pragma unroll
  for (int i = 0; i < 16; ++i) {
    const size_t g = gbase + (size_t)(sg * 16 + i) * ROWF;
    kr[i] = keys[g];
    vr[i] = values[g];
  }
  // ---- convert + LDS write ----
  float kpart = 0.f;
#pragma unroll
  for (int i = 0; i < 16; i += 4) {
    us4 wk, wvv;
#pragma unroll
    for (int j = 0; j < 4; ++j) {
      const float kf = fmap(kr[i + j]);
      kpart += kf;
      wk[j] = f2bf(kf);
      wvv[j] = f2bf(vr[i + j]);
    }
    *(us4*)&Kt[sidx(d, sg * 16 + i)] = wk;
    *(us4*)&Vt[sidx(d, sg * 16 + i)] = wvv;
  }
  __syncthreads();  // B1: tiles + kacc zero-init visible

  atomicAdd(&kacc[d], kpart);  // 4 adders per column

  // swapped MFMA: lane holds T[e = arow][d = nt*16 + lg*4 + r]
  const bf16x8 av0 = *(const bf16x8*)&Vt[sidx(arow, lg * 8)];
  const bf16x8 av1 = *(const bf16x8*)&Vt[sidx(arow, (lg + 4) * 8)];
  us4 tf[4];
#pragma unroll
  for (int nt = 0; nt < 4; ++nt) {
    const int brow = nt * 16 + lane15;   // d-window
    f32x4 acc = {0.f, 0.f, 0.f, 0.f};
    acc = MFMA(*(const bf16x8*)&Kt[sidx(brow, lg * 8)], av0, acc);
    acc = MFMA(*(const bf16x8*)&Kt[sidx(brow, (lg + 4) * 8)], av1, acc);
#pragma unroll
    for (int r = 0; r < 4; ++r) tf[nt][r] = f2bf(acc[r]);
  }
  __syncthreads();  // B2: all Kt/Vt reads done -> Kt reusable as T tile

  // scatter frags into Kt (swizzled image), then linear coalesced copy out
#pragma unroll
  for (int nt = 0; nt < 4; ++nt)
    *(us4*)&Kt[sidx(arow, nt * 16 + lg * 4)] = tf[nt];
  __syncthreads();  // B3: T tile complete; atomics drained

  {
    unsigned short* Tp = Tws + (size_t)bid * 4096;
#pragma unroll
    for (int it = 0; it < 2; ++it) {
      const int i8 = (tid + it * 256) * 8;
      *(uint4*)&Tp[i8] = *(const uint4*)&Kt[i8];
    }
  }
  if (tid < 64) Kcs[(size_t)bid * 64 + tid] = kacc[tid];
}

// ---------------- Pass B: in-place exclusive prefix over chunks (depth 32, 4-wide) ----------------
// Elementwise at fixed linear index; the swizzled image is transparent here.
__global__ __launch_bounds__(256) void k_scan(unsigned short* __restrict__ Tws,
                                              float* __restrict__ Kcs) {
  const int tid = threadIdx.x;
  if (blockIdx.x < 512) {
    const int gid = blockIdx.x * 256 + tid;          // 0 .. 131071
    const int nh = gid >> 12, de = gid & 4095;
    unsigned short* p = Tws + (size_t)nh * NC_ * 4096 + de;
    float run = 0.f;
    for (int s = 0; s < 32; ++s) {
      const float x0 = bf2f(p[(size_t)(s * 4 + 0) * 4096]);
      const float x1 = bf2f(p[(size_t)(s * 4 + 1) * 4096]);
      const float x2 = bf2f(p[(size_t)(s * 4 + 2) * 4096]);
      const float x3 = bf2f(p[(size_t)(s * 4 + 3) * 4096]);
      p[(size_t)(s * 4 + 0) * 4096] = f2bf(run);
      p[(size_t)(s * 4 + 1) * 4096] = f2bf(run + x0);
      p[(size_t)(s * 4 + 2) * 4096] = f2bf(run + x0 + x1);
      p[(size_t)(s * 4 + 3) * 4096] = f2bf(run + x0 + x1 + x2);
      run += x0 + x1 + x2 + x3;
    }
  } else {
    const int gid = (blockIdx.x - 512) * 256 + tid;  // 0 .. 2047
    const int nh = gid >> 6, d = gid & 63;
    float* p = Kcs + (size_t)nh * NC_ * 64 + d;
    float run = 0.f;
    for (int s = 0; s < 32; ++s) {
      const float x0 = p[(size_t)(s * 4 + 0) * 64];
      const float x1 = p[(size_t)(s * 4 + 1) * 64];
      const float x2 = p[(size_t)(s * 4 + 2) * 64];
      const float x3 = p[(size_t)(s * 4 + 3) * 64];
      p[(size_t)(s * 4 + 0) * 64] = run;
      p[(size_t)(s * 4 + 1) * 64] = run + x0;
      p[(size_t)(s * 4 + 2) * 64] = run + x0 + x1;
      p[(size_t)(s * 4 + 3) * 64] = run + x0 + x1 + x2;
      run += x0 + x1 + x2 + x3;
    }
  }
}

// ---------------- Pass C: per-chunk output; prefetch-all staging ----------------
__global__ __launch_bounds__(256, 4) void k_output(const float* __restrict__ queries,
                                                   const float* __restrict__ keys,
                                                   const float* __restrict__ values,
                                                   const unsigned short* __restrict__ Pws,
                                                   const float* __restrict__ Kpre,
                                                   float* __restrict__ out) {
  __shared__ __align__(16) unsigned short Ks[64 * 64];  // K row-major (fmap); after B2: attn rows
  __shared__ __align__(16) unsigned short Vt[64 * 64];  // V^T [e][s]
  __shared__ __align__(16) unsigned short St[64 * 64];  // S^T prefix [e][d] (swizzled image)
  __shared__ float kpre[64];

  // XCD-aware swizzle: 4096 % 8 == 0 -> bijective
  const int wg = blockIdx.x;
  const int bid = (wg & 7) * (NH_ * NC_ / 8) + (wg >> 3);
  const int nh = bid / NC_, c = bid % NC_;
  const int n = nh / H_, h = nh % H_;
  const int tid = threadIdx.x;
  const int lane = tid & 63;
  const int wv = tid >> 6;
  const int lane15 = lane & 15, lg = lane >> 4;
  const int t0w = wv * 16;
  const int trow = t0w + lane15;          // this lane's attn/output row (wave-local)
  const int l0 = c * CHK;

  // ---- prefetch phase: issue ALL global loads into registers ----
  // Q (4 x float4, row trow)
  const size_t qg = ((size_t)(n * L_ + l0 + trow)) * ROWF + h * 64;
  const float4 q0 = *(const float4*)&queries[qg + lg * 8];
  const float4 q1 = *(const float4*)&queries[qg + lg * 8 + 4];
  const float4 q2 = *(const float4*)&queries[qg + 32 + lg * 8];
  const float4 q3 = *(const float4*)&queries[qg + 32 + lg * 8 + 4];
  // K rows (4 x float4, coalesced)
  const int r0 = tid >> 4, c4 = (tid & 15) * 4;
  float4 kr[4];
#pragma unroll
  for (int rep = 0; rep < 4; ++rep)
    kr[rep] = *(const float4*)&keys[((size_t)(n * L_ + l0 + r0 + rep * 16)) * ROWF + h * 64 + c4];
  // V^T (16 scalar, coalesced across lanes)
  const int d = tid & 63, sg = tid >> 6;
  const size_t vbase = ((size_t)(n * L_ + l0)) * ROWF + h * 64 + d;
  float vr[16];
#pragma unroll
  for (int i = 0; i < 16; ++i) vr[i] = values[vbase + (size_t)(sg * 16 + i) * ROWF];
  // St (2 x uint4 linear) + kpre
  const size_t tb = (size_t)bid * 4096;
  const uint4 st0 = *(const uint4*)&Pws[tb + tid * 8];
  const uint4 st1 = *(const uint4*)&Pws[tb + (tid + 256) * 8];
  const float kp = (tid < 64) ? Kpre[(size_t)bid * 64 + tid] : 0.f;

  // ---- convert + LDS writes ----
  bf16x8 qf0, qf1;
  qf0[0] = (short)f2bf(fmap(q0.x)); qf0[1] = (short)f2bf(fmap(q0.y));
  qf0[2] = (short)f2bf(fmap(q0.z)); qf0[3] = (short)f2bf(fmap(q0.w));
  qf0[4] = (short)f2bf(fmap(q1.x)); qf0[5] = (short)f2bf(fmap(q1.y));
  qf0[6] = (short)f2bf(fmap(q1.z)); qf0[7] = (short)f2bf(fmap(q1.w));
  qf1[0] = (short)f2bf(fmap(q2.x)); qf1[1] = (short)f2bf(fmap(q2.y));
  qf1[2] = (short)f2bf(fmap(q2.z)); qf1[3] = (short)f2bf(fmap(q2.w));
  qf1[4] = (short)f2bf(fmap(q3.x)); qf1[5] = (short)f2bf(fmap(q3.y));
  qf1[6] = (short)f2bf(fmap(q3.z)); qf1[7] = (short)f2bf(fmap(q3.w));
#pragma unroll
  for (int rep = 0; rep < 4; ++rep) {
    us4 uk;
    uk[0] = f2bf(fmap(kr[rep].x)); uk[1] = f2bf(fmap(kr[rep].y));
    uk[2] = f2bf(fmap(kr[rep].z)); uk[3] = f2bf(fmap(kr[rep].w));
    *(us4*)&Ks[sidx(r0 + rep * 16, c4)] = uk;
  }
#pragma unroll
  for (int i = 0; i < 16; i += 4) {
    us4 w;
#pragma unroll
    for (int j = 0; j < 4; ++j) w[j] = f2bf(vr[i + j]);
    *(us4*)&Vt[sidx(d, sg * 16 + i)] = w;
  }
  *(uint4*)&St[tid * 8] = st0;
  *(uint4*)&St[(tid + 256) * 8] = st1;
  if (tid < 64) kpre[tid] = kp;
  __syncthreads();  // B1: all tiles + kpre visible

  // ---- QK^T, swapped: lane holds attn[t = trow][s = nt*16 + lg*4 + r] ----
  f32x4 aT[4];
#pragma unroll
  for (int nt = 0; nt < 4; ++nt) {
    const int srow = nt * 16 + lane15;
    f32x4 a = {0.f, 0.f, 0.f, 0.f};
    a = MFMA(*(const bf16x8*)&Ks[sidx(srow, lg * 8)], qf0, a);
    a = MFMA(*(const bf16x8*)&Ks[sidx(srow, (lg + 4) * 8)], qf1, a);
    aT[nt] = a;
  }
  // zden inter-chunk term: in-register dot Q[trow] . kpre
  float zp = 0.f;
#pragma unroll
  for (int j = 0; j < 8; ++j) zp += bf2f((unsigned short)qf0[j]) * kpre[lg * 8 + j];
#pragma unroll
  for (int j = 0; j < 8; ++j) zp += bf2f((unsigned short)qf1[j]) * kpre[32 + lg * 8 + j];

  __syncthreads();  // B2: all waves' Ks reads done (Ks becomes the attn buffer)

  // ---- mask + rowsum + attn rows into Ks (wave-local rows) ----
  float rs = 0.f;
#pragma unroll
  for (int nt = 0; nt < 4; ++nt) {
    us4 w;
#pragma unroll
    for (int r = 0; r < 4; ++r) {
      const int s = nt * 16 + lg * 4 + r;
      const float v = (s <= trow) ? aT[nt][r] : 0.f;
      rs += v;
      w[r] = f2bf(v);
    }
    *(us4*)&Ks[sidx(trow, nt * 16 + lg * 4)] = w;
  }
  // denominator for row trow: reduce the 4 lg-partials; zv stays lane-local
  float den = rs + zp;
  den += __shfl_xor(den, 16);
  den += __shfl_xor(den, 32);
  const float zv = 1.f / (den + EPSF);

  // ---- out^T-frags: lane holds out[trow][e = nt*16 + lg*4 + r] -> float4 stores ----
  const bf16x8 af0 = *(const bf16x8*)&Ks[sidx(trow, lg * 8)];
  const bf16x8 af1 = *(const bf16x8*)&Ks[sidx(trow, 32 + lg * 8)];
  const size_t obase = ((size_t)(n * L_ + l0 + trow)) * ROWF + h * 64;
#pragma unroll
  for (int nt = 0; nt < 4; ++nt) {
    const int brow = nt * 16 + lane15;   // Vt/St row (e) window
    f32x4 o = {0.f, 0.f, 0.f, 0.f};
    o = MFMA(*(const bf16x8*)&Vt[sidx(brow, lg * 8)], af0, o);
    o = MFMA(*(const bf16x8*)&Vt[sidx(brow, (lg + 4) * 8)], af1, o);
    o = MFMA(*(const bf16x8*)&St[sidx(brow, lg * 8)], qf0, o);
    o = MFMA(*(const bf16x8*)&St[sidx(brow, (lg + 4) * 8)], qf1, o);
    const float4 w = make_float4(o[0] * zv, o[1] * zv, o[2] * zv, o[3] * zv);
    *(float4*)&out[obase + nt * 16 + lg * 4] = w;
  }
}

extern "C" void kernel_launch(void* const* d_in, const int* in_sizes, int n_in,
                              void* d_out, int out_size, void* d_ws, size_t ws_size,
                              hipStream_t stream) {
  const float* queries = (const float*)d_in[0];
  const float* keys    = (const float*)d_in[1];
  const float* values  = (const float*)d_in[2];
  float* out = (float*)d_out;

  // workspace layout:
  //  Tws [NH_*NC_][4096] bf16  (chunk totals -> in-place exclusive prefixes; swizzled image)
  //  Kcs [NH_*NC_][64]   fp32  (chunk colsums -> exclusive prefixes)
  const size_t t_elems = (size_t)NH_ * NC_ * 4096;
  const size_t k_elems = (size_t)NH_ * NC_ * 64;
  if (ws_size < t_elems * 2 + k_elems * 4) return;
  unsigned short* Tws = (unsigned short*)d_ws;
  float* Kcs = (float*)(Tws + t_elems);

  hipLaunchKernelGGL(k_chunk_tot, dim3(NH_ * NC_), dim3(256), 0, stream, keys, values, Tws, Kcs);
  hipLaunchKernelGGL(k_scan, dim3(512 + 8), dim3(256), 0, stream, Tws, Kcs);
  hipLaunchKernelGGL(k_output, dim3(NH_ * NC_), dim3(256), 0, stream,
                     queries, keys, values, Tws, Kcs, out);
}